// Round 11
// baseline (312.558 us; speedup 1.0000x reference)
//
#include <hip/hip_runtime.h>
#include <hip/hip_bf16.h>
#include <math.h>

// ---------- types / helpers ----------
typedef short short8 __attribute__((ext_vector_type(8)));
typedef float floatx4 __attribute__((ext_vector_type(4)));
typedef unsigned int uintx4 __attribute__((ext_vector_type(4)));
typedef int intx2 __attribute__((ext_vector_type(2)));

typedef __attribute__((address_space(1))) unsigned int as1_u32;
typedef __attribute__((address_space(3))) unsigned int as3_u32;

__device__ __forceinline__ void load_lds16(const void* g, void* l) {
  // async 16B/lane global->LDS; HW dest = wave-uniform base + lane*16
  __builtin_amdgcn_global_load_lds((const as1_u32*)g, (as3_u32*)l, 16, 0, 0);
}

__device__ __forceinline__ unsigned short f2bf(float f) {
  __bf16 h = (__bf16)f;
  return __builtin_bit_cast(unsigned short, h);
}

__device__ __forceinline__ unsigned int pack_bf16(float a, float b) {
  // compiler fuses to v_cvt_pk_bf16_f32 (lo = a, hi = b)
  return (unsigned int)f2bf(a) | ((unsigned int)f2bf(b) << 16);
}

#define MFMA16(a, b, c) __builtin_amdgcn_mfma_f32_16x16x32_bf16(a, b, c, 0, 0, 0)

// ---------- constants ----------
#define TB 2
#define TT 2048
#define TC 2048
#define QKN 2560    // qk row stride: 2048 Q + 512 K
#define KOFF 2048
#define SCALE_Q 0.18033688f  // (1/8) * log2(e), folded into Q at projection

// ---------- 0: cast fp32 -> bf16 (x, packed Wqkv, Wo) + rope table ----------
__global__ __launch_bounds__(256) void cast_all(
    const float* __restrict__ x, const float* __restrict__ wq,
    const float* __restrict__ wk, const float* __restrict__ wv,
    const float* __restrict__ wo,
    unsigned short* __restrict__ xb, unsigned short* __restrict__ wqkv,
    unsigned short* __restrict__ wob, float2* __restrict__ ropeTab) {
  // rope table: 2048 t x 32 d (cos,sin) = 512 KB, built by first 256 blocks
  if (blockIdx.x < 256) {
    const int idx = blockIdx.x * 256 + threadIdx.x;  // t*32+d
    const int t = idx >> 5, d = idx & 31;
    const float inv = exp2f((float)d * -0.4152410119f);  // 10000^(-d/32)
    float sn, cs;
    sincosf((float)t * inv, &sn, &cs);
    ropeTab[idx] = make_float2(cs, sn);
  }
  long i4 = (long)blockIdx.x * 256 + threadIdx.x;  // float4 index
  const float* src;
  unsigned short* dst;
  if (i4 < 2097152)      { src = x;  dst = xb; }
  else if (i4 < 3145728) { src = wq; dst = wqkv;           i4 -= 2097152; }
  else if (i4 < 3407872) { src = wk; dst = wqkv + 4194304; i4 -= 3145728; }
  else if (i4 < 3670016) { src = wv; dst = wqkv + 5242880; i4 -= 3407872; }
  else                   { src = wo; dst = wob;            i4 -= 3670016; }
  float4 v = ((const float4*)src)[i4];
  ushort4 o;
  o.x = f2bf(v.x); o.y = f2bf(v.y); o.z = f2bf(v.z); o.w = f2bf(v.w);
  ((ushort4*)dst)[i4] = o;
}

// ============================================================================
// 1: QKV GEMM -- 256(M)x192(N) tile, grid (16,16) = 256 blocks (100% CU).
// R11: ONE barrier per phase (was 2). The open barrier between each phase's
// ds_reads and MFMA forced lockstep -- LDS pipe and MFMA pipe never
// overlapped across the 2 waves/SIMD (~1000 cyc/phase of the measured 2040
// was barrier rendezvous). New phase: [reads; stage; lgkm(0); MFMA;
// (vmcnt ph2/ph4); BARRIER]. Publish moves to the CLOSE barrier.
// Hazard audit (phases fully separated by the close barriers):
//  ph1 stage buf1.B: last read of buf1.B = prev ph4 bfR, sep by prev BAR4.
//  ph2 stage buf0.A: last read = ph1 af, drained by ph1 lgkm + BAR1.
//  ph2 reads cb0.B || stage buf0.A -- disjoint regions.
//  ph3 stage buf0.B: last read = ph2 bfR, sep by BAR2.  ph4 sym.
// FIFO queue-sim (loads: B=3, A=4): ph2 vmcnt(4): [B(tO)3,A(tE2)4]=7 ->
// retires B(tO); with A(tO) retired at prev ph4 -> buf1 complete at BAR2.
// ph4 vmcnt(4): [A(tE2)4,B(tE2)3,A(tO2)4]=11 -> retires 7 = A+B(tE2) ->
// buf0 complete at BAR4. Prologue establishes the 4-outstanding invariant;
// tail vmcnt(0). MFMA order unchanged -> numerics identical.
// ============================================================================
#define QKV_MFMA(BF)                                                           \
  __builtin_amdgcn_s_setprio(1);                                               \
  _Pragma("unroll") for (int i_ = 0; i_ < 4; ++i_) {                           \
    _Pragma("unroll") for (int j_ = 0; j_ < 3; ++j_) {                         \
      acc[i_][JBASE + j_] = MFMA16(af[i_][0], BF[j_][0], acc[i_][JBASE + j_]); \
      acc[i_][JBASE + j_] = MFMA16(af[i_][1], BF[j_][1], acc[i_][JBASE + j_]); \
    }                                                                          \
  }                                                                            \
  __builtin_amdgcn_s_setprio(0);

__global__ __launch_bounds__(512, 2) void gemm_qkv(const unsigned short* __restrict__ A,
                                                   const unsigned short* __restrict__ Bw,
                                                   unsigned short* __restrict__ qk,
                                                   unsigned short* __restrict__ vT,
                                                   const float2* __restrict__ ropeTab) {
  extern __shared__ char dynlds[];
  const int K = 2048;
  const int tid = threadIdx.x;
  const int lane = tid & 63, w = tid >> 6;
  const int quad = lane >> 4, l15 = lane & 15;
  const int wm = w >> 1, wn = w & 1;

  // XCD-bijective swizzle: 256 blocks, 32 per XCD
  const int lin = blockIdx.y * 16 + blockIdx.x;
  const int wg = (lin & 7) * 32 + (lin >> 3);
  const int m0 = (wg >> 4) * 256;
  const int n0 = (wg & 15) * 192;

  floatx4 acc[4][6];
#pragma unroll
  for (int i = 0; i < 4; ++i)
#pragma unroll
    for (int j = 0; j < 6; ++j) acc[i][j] = (floatx4){0.f, 0.f, 0.f, 0.f};

  const int srow8 = tid >> 3;
  const int schk = (tid & 7) ^ (srow8 & 7);
  const unsigned short* aS = A + (size_t)(m0 + srow8) * K + schk * 8;
  const unsigned short* bS = Bw + (size_t)(n0 + srow8) * K + schk * 8;

  const int key0 = (quad ^ (l15 & 7)) << 4;
  const int key1 = ((4 + quad) ^ (l15 & 7)) << 4;
  const int rdA = (wm * 64 + l15) * 128;      // A region [0, 32768)
  const int rdBl = 32768 + l15 * 128;         // B region [32768, 57344)

  // B slot -> 16-col unit within the 192-col tile (in-wave rope pairing)
  constexpr int F0[6] = {0, 2, 1, 3, 4, 6};
  constexpr int F1[6] = {5, 7, 8, 10, 9, 11};

  auto stageA = [&](int bb, int tt) {  // 4 loads = 32KB (rows 0-255)
    char* d = dynlds + bb * 57344;
    const unsigned short* s = aS + (size_t)tt * 64;
    load_lds16(s, d + tid * 16);
    load_lds16(s + (size_t)64 * K, d + 8192 + tid * 16);
    load_lds16(s + (size_t)128 * K, d + 16384 + tid * 16);
    load_lds16(s + (size_t)192 * K, d + 24576 + tid * 16);
  };
  auto stageB = [&](int bb, int tt) {  // 3 loads = 24KB (rows 0-191)
    char* d = dynlds + bb * 57344 + 32768;
    const unsigned short* s = bS + (size_t)tt * 64;
    load_lds16(s, d + tid * 16);
    load_lds16(s + (size_t)64 * K, d + 8192 + tid * 16);
    load_lds16(s + (size_t)128 * K, d + 16384 + tid * 16);
  };

  // prologue: t0{A,B}->buf0, t1{A}->buf1 (11 loads); vmcnt(4) retires t0.
  stageA(0, 0); stageB(0, 0); stageA(1, 1);
  asm volatile("s_waitcnt vmcnt(4)" ::: "memory");
  __builtin_amdgcn_s_barrier();

  short8 af[4][2], bfL[3][2], bfR[3][2];
  const char* cb0 = dynlds;
  const char* cb1 = dynlds + 57344;
  const int NIT = K >> 7;  // 2 K-tiles per iteration

  for (int it = 0; it < NIT; ++it) {
    const int tO = it * 2 + 1, tE2 = it * 2 + 2, tO2 = it * 2 + 3;
    const bool STG = (it < NIT - 1);

    // ---- ph1: read af+bfL (buf0, 14); stage B(tO); lgkm; MFMA-L; BAR ----
#pragma unroll
    for (int i = 0; i < 4; ++i) {
      af[i][0] = *(const short8*)(cb0 + rdA + i * 2048 + key0);
      af[i][1] = *(const short8*)(cb0 + rdA + i * 2048 + key1);
    }
#pragma unroll
    for (int j = 0; j < 3; ++j) {
      const int fe = wn ? F1[j] : F0[j];
      bfL[j][0] = *(const short8*)(cb0 + rdBl + fe * 2048 + key0);
      bfL[j][1] = *(const short8*)(cb0 + rdBl + fe * 2048 + key1);
    }
    stageB(1, tO);
    asm volatile("s_waitcnt lgkmcnt(0)" ::: "memory");
    {
      const int JBASE = 0;
      QKV_MFMA(bfL)
    }
    __builtin_amdgcn_s_barrier();

    // ---- ph2: read bfR (buf0, 6); stage A(tE2); lgkm; MFMA-R; vmcnt; BAR ----
#pragma unroll
    for (int j = 0; j < 3; ++j) {
      const int fe = wn ? F1[3 + j] : F0[3 + j];
      bfR[j][0] = *(const short8*)(cb0 + rdBl + fe * 2048 + key0);
      bfR[j][1] = *(const short8*)(cb0 + rdBl + fe * 2048 + key1);
    }
    if (STG) stageA(0, tE2);
    asm volatile("s_waitcnt lgkmcnt(0)" ::: "memory");
    {
      const int JBASE = 3;
      QKV_MFMA(bfR)
    }
    if (STG) asm volatile("s_waitcnt vmcnt(4)" ::: "memory");
    else     asm volatile("s_waitcnt vmcnt(0)" ::: "memory");
    __builtin_amdgcn_s_barrier();  // publishes buf1

    // ---- ph3: read af+bfL (buf1, 14); stage B(tE2); lgkm; MFMA-L; BAR ----
#pragma unroll
    for (int i = 0; i < 4; ++i) {
      af[i][0] = *(const short8*)(cb1 + rdA + i * 2048 + key0);
      af[i][1] = *(const short8*)(cb1 + rdA + i * 2048 + key1);
    }
#pragma unroll
    for (int j = 0; j < 3; ++j) {
      const int fe = wn ? F1[j] : F0[j];
      bfL[j][0] = *(const short8*)(cb1 + rdBl + fe * 2048 + key0);
      bfL[j][1] = *(const short8*)(cb1 + rdBl + fe * 2048 + key1);
    }
    if (STG) stageB(0, tE2);
    asm volatile("s_waitcnt lgkmcnt(0)" ::: "memory");
    {
      const int JBASE = 0;
      QKV_MFMA(bfL)
    }
    __builtin_amdgcn_s_barrier();

    // ---- ph4: read bfR (buf1, 6); stage A(tO2); lgkm; MFMA-R; vmcnt; BAR ----
#pragma unroll
    for (int j = 0; j < 3; ++j) {
      const int fe = wn ? F1[3 + j] : F0[3 + j];
      bfR[j][0] = *(const short8*)(cb1 + rdBl + fe * 2048 + key0);
      bfR[j][1] = *(const short8*)(cb1 + rdBl + fe * 2048 + key1);
    }
    if (STG) stageA(1, tO2);
    asm volatile("s_waitcnt lgkmcnt(0)" ::: "memory");
    {
      const int JBASE = 3;
      QKV_MFMA(bfR)
    }
    if (STG) asm volatile("s_waitcnt vmcnt(4)" ::: "memory");
    else     asm volatile("s_waitcnt vmcnt(0)" ::: "memory");
    __builtin_amdgcn_s_barrier();  // publishes buf0
  }

  // ---- epilogue: per-pair region branch (head-uniform by construction) ----
#pragma unroll
  for (int i = 0; i < 4; ++i) {
    const int rowb = m0 + wm * 64 + i * 16 + quad * 4;
    const int tb = rowb & (TT - 1);
#pragma unroll
    for (int jp = 0; jp < 6; jp += 2) {
      const int fe = wn ? F1[jp] : F0[jp];
      const int col = n0 + fe * 16 + l15;
      if (col < QKN) {
        // Q or K head: RoPE (pair partner is col+32, slot jp+1)
        const float qscale = (col < KOFF) ? SCALE_Q : 1.0f;
        const int d = (fe & 3) * 16 + l15;  // 0..31
#pragma unroll
        for (int r = 0; r < 4; ++r) {
          const float2 cssn = ropeTab[(tb + r) * 32 + d];
          const float a = acc[i][jp][r], b2 = acc[i][jp + 1][r];
          const float qa = (a * cssn.x - b2 * cssn.y) * qscale;
          const float qb = (b2 * cssn.x + a * cssn.y) * qscale;
          unsigned short* p = qk + (size_t)(rowb + r) * QKN + col;
          p[0] = f2bf(qa);
          p[32] = f2bf(qb);
        }
      } else {
        // V head: transposed packed store, both slots independently
#pragma unroll
        for (int jj = jp; jj < jp + 2; ++jj) {
          const int fv = wn ? F1[jj] : F0[jj];
          const int colv = n0 + fv * 16 + l15;
          ushort4 pk;
          pk.x = f2bf(acc[i][jj][0]); pk.y = f2bf(acc[i][jj][1]);
          pk.z = f2bf(acc[i][jj][2]); pk.w = f2bf(acc[i][jj][3]);
          *(ushort4*)(vT + (size_t)(colv - 2560) * 4096 + rowb) = pk;
        }
      }
    }
  }
}

// ============================================================================
// 1b: output projection NT GEMM (f32 out) -- 256(M)x128(N) tile, 256 blocks.
// R11: same 1-barrier-per-phase restructure as gemm_qkv (audit identical;
// loads B=2, A=4: ph2 vmcnt(4) queue [B2,A4]=6 retires B; ph4 vmcnt(4)
// queue [A4,B2,A4]=10 retires 6 -> buffer complete at close barrier).
// ============================================================================
#define NT_MFMA(J0, BF)                                                        \
  __builtin_amdgcn_s_setprio(1);                                               \
  _Pragma("unroll") for (int i_ = 0; i_ < 4; ++i_) {                           \
    _Pragma("unroll") for (int j_ = 0; j_ < 2; ++j_) {                         \
      acc[i_][(J0) + j_] = MFMA16(af[i_][0], BF[j_][0], acc[i_][(J0) + j_]);   \
      acc[i_][(J0) + j_] = MFMA16(af[i_][1], BF[j_][1], acc[i_][(J0) + j_]);   \
    }                                                                          \
  }                                                                            \
  __builtin_amdgcn_s_setprio(0);

__global__ __launch_bounds__(512, 2) void gemm_nt_f32(const unsigned short* __restrict__ A,
                                                      const unsigned short* __restrict__ Bw,
                                                      float* __restrict__ C,
                                                      int M, int N, int Kdim) {
  extern __shared__ char dynlds[];
  const int K = 2048;
  const int tid = threadIdx.x;
  const int lane = tid & 63, w = tid >> 6;
  const int quad = lane >> 4, l15 = lane & 15;
  const int wm = w >> 1, wn = w & 1;

  // XCD-bijective swizzle: 256 blocks, 32 per XCD
  const int lin = blockIdx.y * 16 + blockIdx.x;
  const int wg = (lin & 7) * 32 + (lin >> 3);
  const int m0 = (wg >> 4) * 256;
  const int n0 = (wg & 15) * 128;

  floatx4 acc[4][4];
#pragma unroll
  for (int i = 0; i < 4; ++i)
#pragma unroll
    for (int j = 0; j < 4; ++j) acc[i][j] = (floatx4){0.f, 0.f, 0.f, 0.f};

  const int srow8 = tid >> 3;
  const int schk = (tid & 7) ^ (srow8 & 7);
  const unsigned short* aS = A + (size_t)(m0 + srow8) * K + schk * 8;
  const unsigned short* bS = Bw + (size_t)(n0 + srow8) * K + schk * 8;

  const int key0 = (quad ^ (l15 & 7)) << 4;
  const int key1 = ((4 + quad) ^ (l15 & 7)) << 4;
  const int rdA = (wm * 64 + l15) * 128;          // A region: [0, 32768)
  const int rdB = 32768 + (wn * 64 + l15) * 128;  // B region: [32768, 49152)

  // stage slot: 0=A0 (rows 0-127), 1=A1 (128-255), 2=B (128 rows)
  auto stage = [&](int bb, int slot, int tt) {
    char* d = dynlds + bb * 49152 + slot * 16384;
    const unsigned short* s =
        (slot == 2 ? bS : aS + (size_t)(slot * 128) * K) + (size_t)tt * 64;
    load_lds16(s, d + tid * 16);
    load_lds16(s + (size_t)64 * K, d + 8192 + tid * 16);
  };

  // prologue: t0{A0,A1,B}->buf0, t1{A0,A1}->buf1 (10 loads); retire t0.
  stage(0, 0, 0); stage(0, 1, 0); stage(0, 2, 0);
  stage(1, 0, 1); stage(1, 1, 1);
  asm volatile("s_waitcnt vmcnt(4)" ::: "memory");
  __builtin_amdgcn_s_barrier();

  short8 af[4][2], bfL[2][2], bfR[2][2];
  const char* cb0 = dynlds;
  const char* cb1 = dynlds + 49152;
  const int NIT = K >> 7;  // 2 K-tiles per iteration

  for (int it = 0; it < NIT; ++it) {
    const int tO = it * 2 + 1, tE2 = it * 2 + 2, tO2 = it * 2 + 3;
    const bool STG = (it < NIT - 1);

    // ---- ph1: read af+bfL (buf0, 12); stage B(tO); lgkm; QL; BAR ----
#pragma unroll
    for (int i = 0; i < 4; ++i) {
      af[i][0] = *(const short8*)(cb0 + rdA + i * 2048 + key0);
      af[i][1] = *(const short8*)(cb0 + rdA + i * 2048 + key1);
    }
#pragma unroll
    for (int j = 0; j < 2; ++j) {
      bfL[j][0] = *(const short8*)(cb0 + rdB + j * 2048 + key0);
      bfL[j][1] = *(const short8*)(cb0 + rdB + j * 2048 + key1);
    }
    stage(1, 2, tO);
    asm volatile("s_waitcnt lgkmcnt(0)" ::: "memory");
    NT_MFMA(0, bfL)
    __builtin_amdgcn_s_barrier();

    // ---- ph2: read bfR (buf0, 4); stage A0,A1(tE2); lgkm; QR; vmcnt; BAR ----
#pragma unroll
    for (int j = 0; j < 2; ++j) {
      bfR[j][0] = *(const short8*)(cb0 + rdB + (2 + j) * 2048 + key0);
      bfR[j][1] = *(const short8*)(cb0 + rdB + (2 + j) * 2048 + key1);
    }
    if (STG) { stage(0, 0, tE2); stage(0, 1, tE2); }
    asm volatile("s_waitcnt lgkmcnt(0)" ::: "memory");
    NT_MFMA(2, bfR)
    if (STG) asm volatile("s_waitcnt vmcnt(4)" ::: "memory");
    else     asm volatile("s_waitcnt vmcnt(0)" ::: "memory");
    __builtin_amdgcn_s_barrier();  // publishes buf1

    // ---- ph3: read af+bfL (buf1, 12); stage B(tE2); lgkm; QL; BAR ----
#pragma unroll
    for (int i = 0; i < 4; ++i) {
      af[i][0] = *(const short8*)(cb1 + rdA + i * 2048 + key0);
      af[i][1] = *(const short8*)(cb1 + rdA + i * 2048 + key1);
    }
#pragma unroll
    for (int j = 0; j < 2; ++j) {
      bfL[j][0] = *(const short8*)(cb1 + rdB + j * 2048 + key0);
      bfL[j][1] = *(const short8*)(cb1 + rdB + j * 2048 + key1);
    }
    if (STG) stage(0, 2, tE2);
    asm volatile("s_waitcnt lgkmcnt(0)" ::: "memory");
    NT_MFMA(0, bfL)
    __builtin_amdgcn_s_barrier();

    // ---- ph4: read bfR (buf1, 4); stage A0,A1(tO2); lgkm; QR; vmcnt; BAR ----
#pragma unroll
    for (int j = 0; j < 2; ++j) {
      bfR[j][0] = *(const short8*)(cb1 + rdB + (2 + j) * 2048 + key0);
      bfR[j][1] = *(const short8*)(cb1 + rdB + (2 + j) * 2048 + key1);
    }
    if (STG) { stage(1, 0, tO2); stage(1, 1, tO2); }
    asm volatile("s_waitcnt lgkmcnt(0)" ::: "memory");
    NT_MFMA(2, bfR)
    if (STG) asm volatile("s_waitcnt vmcnt(4)" ::: "memory");
    else     asm volatile("s_waitcnt vmcnt(0)" ::: "memory");
    __builtin_amdgcn_s_barrier();  // publishes buf0
  }

  // ---- epilogue: plain f32 store ----
#pragma unroll
  for (int i = 0; i < 4; ++i) {
    const int row = m0 + wm * 64 + i * 16 + quad * 4;
#pragma unroll
    for (int j = 0; j < 4; ++j) {
      const int col = n0 + wn * 64 + j * 16 + l15;
#pragma unroll
      for (int r = 0; r < 4; ++r)
        C[(size_t)(row + r) * N + col] = acc[i][j][r];
    }
  }
}

// ---------- 2: causal flash attention v11 ----------
// grid (32, 2, 16) = (head, batch, qz); qt = 15 - qz (heavy-first LPT order).
// P never touches LDS: exp2 -> cvt_pk pairs -> 4x4 quad-group transpose via
// permlane32_swap + permlane16_swap. LDS 32768 B.
// v11: launch_bounds (256,4) -- unified reg use ~80 arch + ~40 acc = 120
// <= 128 cap, so 4 blocks/CU (grid = exactly 4x256) instead of 3. If the
// allocator spills (WRITE_SIZE balloons), revert to (256,3).
// raw v_exp_f32 via __builtin_amdgcn_exp2f; epilogue divide -> rcp+mul.
__global__ __launch_bounds__(256, 4) void attn_kernel(const unsigned short* __restrict__ qk,
                                                      const unsigned short* __restrict__ vT,
                                                      unsigned short* __restrict__ attn) {
  const int h = blockIdx.x, b = blockIdx.y;
  const int qt = 15 - (int)blockIdx.z;  // heavy-first dispatch
  const int hk = h >> 2;
  const int tid = threadIdx.x;
  const int w = tid >> 6, lane = tid & 63, quad = lane >> 4, l15 = lane & 15;

  __shared__ char lds[32768];

  const int srow = tid >> 3;                    // staging row
  const int sgrp = ((tid & 7) ^ (srow & 7));    // swizzled source col-group
  const int relbase = w * 32 + l15;             // for causal mask (q local)

  const short8 ones = {16256, 16256, 16256, 16256, 16256, 16256, 16256, 16256};  // bf16 1.0

  const size_t rowQ = (size_t)(b * TT + qt * 128);

  // ---- stage Q tile (128x64, swizzled) into K/V region ----
  {
    const unsigned short* qsrc = qk + (rowQ + srow) * QKN + h * 64 + sgrp * 8;
#pragma unroll
    for (int p = 0; p < 4; ++p)
      load_lds16(qsrc + (size_t)p * 32 * QKN, lds + p * 4096 + tid * 16);
  }
  __syncthreads();
  short8 qf[2][2];  // B-operand frags: Q[q=l15(+i*16)][d=ks*32+quad*8..]
#pragma unroll
  for (int i = 0; i < 2; ++i)
#pragma unroll
    for (int ks = 0; ks < 2; ++ks)
      qf[i][ks] = *(const short8*)(lds + (w * 32 + i * 16 + l15) * 128 +
                                   ((((ks << 2) + quad) ^ (l15 & 7)) << 4));
  __syncthreads();  // all waves done reading Q before K(0)/V(0) overwrite

  floatx4 accO[2][4], accL[2];
#pragma unroll
  for (int i = 0; i < 2; ++i) {
    accL[i] = (floatx4){0.f, 0.f, 0.f, 0.f};
#pragma unroll
    for (int j = 0; j < 4; ++j) accO[i][j] = (floatx4){0.f, 0.f, 0.f, 0.f};
  }

  // ---- prefetch pointers (advance by one 64-row tile per step) ----
  const unsigned short* kptr =
      qk + (size_t)(b * TT + srow) * QKN + KOFF + hk * 64 + sgrp * 8;
  const unsigned short* vptr =
      vT + (size_t)(hk * 64 + srow) * 4096 + b * TT + sgrp * 8;

  // ---- prologue: stage tile 0 into buf0 ----
  load_lds16(kptr, lds + tid * 16);
  load_lds16(kptr + (size_t)32 * QKN, lds + 4096 + tid * 16);
  load_lds16(vptr, lds + 16384 + tid * 16);
  load_lds16(vptr + (size_t)32 * 4096, lds + 16384 + 4096 + tid * 16);
  kptr += (size_t)64 * QKN;
  vptr += 64;
  __syncthreads();

  // one kv-tile step; BUF/PREF/MREL become compile-time after inlining
  auto step = [&](const int BUF, const bool PREF, const int MREL) {
    if (PREF) {
      char* kd = lds + ((BUF ^ 1) * 8192);
      char* vd = lds + 16384 + ((BUF ^ 1) * 8192);
      load_lds16(kptr, kd + tid * 16);
      load_lds16(kptr + (size_t)32 * QKN, kd + 4096 + tid * 16);
      load_lds16(vptr, vd + tid * 16);
      load_lds16(vptr + (size_t)32 * 4096, vd + 4096 + tid * 16);
      kptr += (size_t)64 * QKN;
      vptr += 64;
    }

    // ---- S^T = K Q^T : D[kk_local][q_local] (scale pre-folded into Q) ----
    const char* Ks = lds + BUF * 8192;
    floatx4 st[2][4];  // [i=q-tile][jm=kk-tile]
    __builtin_amdgcn_s_setprio(1);
#pragma unroll
    for (int jm = 0; jm < 4; ++jm) {
      const int krow = jm * 16 + l15;
      const short8 kf0 = *(const short8*)(Ks + krow * 128 + ((quad ^ (l15 & 7)) << 4));
      const short8 kf1 = *(const short8*)(Ks + krow * 128 + (((4 + quad) ^ (l15 & 7)) << 4));
#pragma unroll
      for (int i = 0; i < 2; ++i) {
        floatx4 z = (floatx4){0.f, 0.f, 0.f, 0.f};
        z = __builtin_amdgcn_mfma_f32_16x16x32_bf16(kf0, qf[i][0], z, 0, 0, 0);
        st[i][jm] = __builtin_amdgcn_mfma_f32_16x16x32_bf16(kf1, qf[i][1], z, 0, 0, 0);
      }
    }
    __builtin_amdgcn_s_setprio(0);

    // ---- hoist V-fragment LDS reads: latency overlaps softmax VALU ----
    const char* Vt = lds + 16384 + BUF * 8192;
    short8 vf[2][4];
#pragma unroll
    for (int ks = 0; ks < 2; ++ks)
#pragma unroll
      for (int jd = 0; jd < 4; ++jd) {
        const int d = jd * 16 + l15;
        vf[ks][jd] = *(const short8*)(Vt + d * 128 +
                                      ((((ks << 2) + quad) ^ (l15 & 7)) << 4));
      }

    // ---- softmax + in-register P transpose ----
    // source: st[i][jm][r] = P[k=jm*16+quad*4+r][q=l15]
    // target: pT[i][ks] = P[q=l15][k=32ks+8quad .. +7] (MFMA A-operand frag)
    short8 pT[2][2];
#pragma unroll
    for (int i = 0; i < 2; ++i) {
      unsigned int U[4][2];  // U[jm][h] = pack(e[2h], e[2h+1])
#pragma unroll
      for (int jm = 0; jm < 4; ++jm) {
        float e0 = __builtin_amdgcn_exp2f(st[i][jm][0]);
        float e1 = __builtin_amdgcn_exp2f(st[i][jm][1]);
        float e2 = __builtin_amdgcn_exp2f(st[i][jm][2]);
        float e3 = __builtin_amdgcn_exp2f(st[i][jm][3]);
        if (MREL >= 0) {
          const int rel = relbase + i * 16 - MREL;  // lane's local q
          const int kg = jm * 16 + quad * 4;
          if (kg > rel) e0 = 0.f;
          if (kg + 1 > rel) e1 = 0.f;
          if (kg + 2 > rel) e2 = 0.f;
          if (kg + 3 > rel) e3 = 0.f;
        }
        U[jm][0] = pack_bf16(e0, e1);
        U[jm][1] = pack_bf16(e2, e3);
      }
      // 4x4 quad-group transpose via permlane32_swap + permlane16_swap
#pragma unroll
      for (int ks = 0; ks < 2; ++ks) {
        uintx4 t;
#pragma unroll
        for (int hh = 0; hh < 2; ++hh) {
          intx2 r32 = __builtin_amdgcn_permlane32_swap(
              (int)U[2 * ks][hh], (int)U[2 * ks + 1][hh], false, false);
          intx2 r16 = __builtin_amdgcn_permlane16_swap(r32[0], r32[1], false, false);
          t[hh] = (unsigned int)r16[0];      // s = 0 + hh  (c0 = 0)
          t[2 + hh] = (unsigned int)r16[1];  // s = 2 + hh  (c0 = 1)
        }
        pT[i][ks] = __builtin_bit_cast(short8, t);
      }
    }

    // ---- O += P V ; l += P . 1 ----
    __builtin_amdgcn_s_setprio(1);
#pragma unroll
    for (int ks = 0; ks < 2; ++ks) {
      accL[0] = __builtin_amdgcn_mfma_f32_16x16x32_bf16(pT[0][ks], ones, accL[0], 0, 0, 0);
      accL[1] = __builtin_amdgcn_mfma_f32_16x16x32_bf16(pT[1][ks], ones, accL[1], 0, 0, 0);
#pragma unroll
      for (int jd = 0; jd < 4; ++jd) {
        accO[0][jd] = __builtin_amdgcn_mfma_f32_16x16x32_bf16(pT[0][ks], vf[ks][jd], accO[0][jd], 0, 0, 0);
        accO[1][jd] = __builtin_amdgcn_mfma_f32_16x16x32_bf16(pT[1][ks], vf[ks][jd], accO[1][jd], 0, 0, 0);
      }
    }
    __builtin_amdgcn_s_setprio(0);
    __syncthreads();  // drains prefetch + protects buffer overwrite
  };

  // steady: 2*qt unmasked tiles (pairs), then 2 masked diagonal tiles
  for (int t2 = 0; t2 < qt; ++t2) {
    step(0, true, -1);
    step(1, true, -1);
  }
  step(0, true, 0);
  step(1, false, 64);

  // ---- epilogue: O * (1/l) -> attn  (accL C-layout rows match accO rows) ----
#pragma unroll
  for (int i2 = 0; i2 < 2; ++i2) {
    floatx4 rl;
#pragma unroll
    for (int r = 0; r < 4; ++r) rl[r] = __builtin_amdgcn_rcpf(accL[i2][r]);
#pragma unroll
    for (int jd = 0; jd < 4; ++jd) {
      const int col = h * 64 + jd * 16 + l15;
#pragma unroll
      for (int r = 0; r < 4; ++r) {
        const size_t row = rowQ + w * 32 + i2 * 16 + quad * 4 + r;
        attn[row * TC + col] = f2bf(accO[i2][jd][r] * rl[r]);
      }
    }
  }
}

// ---------- launch ----------
extern "C" void kernel_launch(void* const* d_in, const int* in_sizes, int n_in,
                              void* d_out, int out_size, void* d_ws, size_t ws_size,
                              hipStream_t stream) {
  const float* x = (const float*)d_in[0];
  const float* Wq = (const float*)d_in[1];
  const float* Wk = (const float*)d_in[2];
  const float* Wv = (const float*)d_in[3];
  const float* Wo = (const float*)d_in[4];
  float* out = (float*)d_out;

  char* ws = (char*)d_ws;
  unsigned short* xb   = (unsigned short*)(ws);               // 4096x2048 bf16
  unsigned short* wqkv = (unsigned short*)(ws + 16777216);    // 3072x2048 bf16
  unsigned short* wob  = (unsigned short*)(ws + 29360128);    // 2048x2048 bf16
  unsigned short* qk   = (unsigned short*)(ws + 37748736);    // 4096x2560 bf16 (Q|K, roped)
  unsigned short* vT   = (unsigned short*)(ws + 58720256);    // 512x4096 bf16 (V transposed)
  unsigned short* attn = (unsigned short*)(ws + 62914560);    // 4096x2048 bf16
  // rope table (512 KB) overlays the attn buffer: written by cast_all, read by
  // gemm_qkv, then overwritten by attn_kernel (all stream-ordered).
  float2* ropeTab = (float2*)(ws + 62914560);
  // total ws use: 79,691,776 bytes

  cast_all<<<18432, 256, 0, stream>>>(x, Wq, Wk, Wv, Wo, xb, wqkv, wob, ropeTab);
  gemm_qkv<<<dim3(16, 16), 512, 114688, stream>>>(xb, wqkv, qk, vT, ropeTab);
  attn_kernel<<<dim3(32, 2, 16), 256, 0, stream>>>(qk, vT, attn);
  gemm_nt_f32<<<dim3(16, 16), 512, 98304, stream>>>(attn, wob, out, 4096, TC, 2048);
}

// Round 12
// 241.311 us; speedup vs baseline: 1.2952x; 1.2952x over previous
//
#include <hip/hip_runtime.h>
#include <hip/hip_bf16.h>
#include <math.h>

// ---------- types / helpers ----------
typedef short short8 __attribute__((ext_vector_type(8)));
typedef float floatx4 __attribute__((ext_vector_type(4)));
typedef unsigned int uintx4 __attribute__((ext_vector_type(4)));
typedef int intx2 __attribute__((ext_vector_type(2)));

typedef __attribute__((address_space(1))) unsigned int as1_u32;
typedef __attribute__((address_space(3))) unsigned int as3_u32;

__device__ __forceinline__ void load_lds16(const void* g, void* l) {
  // async 16B/lane global->LDS; HW dest = wave-uniform base + lane*16
  __builtin_amdgcn_global_load_lds((const as1_u32*)g, (as3_u32*)l, 16, 0, 0);
}

__device__ __forceinline__ unsigned short f2bf(float f) {
  __bf16 h = (__bf16)f;
  return __builtin_bit_cast(unsigned short, h);
}

__device__ __forceinline__ unsigned int pack_bf16(float a, float b) {
  // compiler fuses to v_cvt_pk_bf16_f32 (lo = a, hi = b)
  return (unsigned int)f2bf(a) | ((unsigned int)f2bf(b) << 16);
}

#define MFMA16(a, b, c) __builtin_amdgcn_mfma_f32_16x16x32_bf16(a, b, c, 0, 0, 0)

// ---------- constants ----------
#define TB 2
#define TT 2048
#define TC 2048
#define QKN 2560    // qk row stride: 2048 Q + 512 K
#define KOFF 2048
#define SCALE_Q 0.18033688f  // (1/8) * log2(e), folded into Q at projection

// ---------- 0: cast fp32 -> bf16 (x, packed Wqkv, Wo) + rope table ----------
__global__ __launch_bounds__(256) void cast_all(
    const float* __restrict__ x, const float* __restrict__ wq,
    const float* __restrict__ wk, const float* __restrict__ wv,
    const float* __restrict__ wo,
    unsigned short* __restrict__ xb, unsigned short* __restrict__ wqkv,
    unsigned short* __restrict__ wob, float2* __restrict__ ropeTab) {
  // rope table: 2048 t x 32 d (cos,sin) = 512 KB, built by first 256 blocks
  if (blockIdx.x < 256) {
    const int idx = blockIdx.x * 256 + threadIdx.x;  // t*32+d
    const int t = idx >> 5, d = idx & 31;
    const float inv = exp2f((float)d * -0.4152410119f);  // 10000^(-d/32)
    float sn, cs;
    sincosf((float)t * inv, &sn, &cs);
    ropeTab[idx] = make_float2(cs, sn);
  }
  long i4 = (long)blockIdx.x * 256 + threadIdx.x;  // float4 index
  const float* src;
  unsigned short* dst;
  if (i4 < 2097152)      { src = x;  dst = xb; }
  else if (i4 < 3145728) { src = wq; dst = wqkv;           i4 -= 2097152; }
  else if (i4 < 3407872) { src = wk; dst = wqkv + 4194304; i4 -= 3145728; }
  else if (i4 < 3670016) { src = wv; dst = wqkv + 5242880; i4 -= 3407872; }
  else                   { src = wo; dst = wob;            i4 -= 3670016; }
  float4 v = ((const float4*)src)[i4];
  ushort4 o;
  o.x = f2bf(v.x); o.y = f2bf(v.y); o.z = f2bf(v.z); o.w = f2bf(v.w);
  ((ushort4*)dst)[i4] = o;
}

// ============================================================================
// 1: QKV GEMM -- 256(M)x192(N) tile, grid (16,16) = 256 blocks (100% CU).
// ONE barrier per phase: [reads; stage; lgkm(0); MFMA; (vmcnt ph2/ph4); BAR].
// Hazard audit + FIFO queue-sim in R11 notes; MFMA order unchanged.
// ============================================================================
#define QKV_MFMA(BF)                                                           \
  __builtin_amdgcn_s_setprio(1);                                               \
  _Pragma("unroll") for (int i_ = 0; i_ < 4; ++i_) {                           \
    _Pragma("unroll") for (int j_ = 0; j_ < 3; ++j_) {                         \
      acc[i_][JBASE + j_] = MFMA16(af[i_][0], BF[j_][0], acc[i_][JBASE + j_]); \
      acc[i_][JBASE + j_] = MFMA16(af[i_][1], BF[j_][1], acc[i_][JBASE + j_]); \
    }                                                                          \
  }                                                                            \
  __builtin_amdgcn_s_setprio(0);

__global__ __launch_bounds__(512, 2) void gemm_qkv(const unsigned short* __restrict__ A,
                                                   const unsigned short* __restrict__ Bw,
                                                   unsigned short* __restrict__ qk,
                                                   unsigned short* __restrict__ vT,
                                                   const float2* __restrict__ ropeTab) {
  extern __shared__ char dynlds[];
  const int K = 2048;
  const int tid = threadIdx.x;
  const int lane = tid & 63, w = tid >> 6;
  const int quad = lane >> 4, l15 = lane & 15;
  const int wm = w >> 1, wn = w & 1;

  // XCD-bijective swizzle: 256 blocks, 32 per XCD
  const int lin = blockIdx.y * 16 + blockIdx.x;
  const int wg = (lin & 7) * 32 + (lin >> 3);
  const int m0 = (wg >> 4) * 256;
  const int n0 = (wg & 15) * 192;

  floatx4 acc[4][6];
#pragma unroll
  for (int i = 0; i < 4; ++i)
#pragma unroll
    for (int j = 0; j < 6; ++j) acc[i][j] = (floatx4){0.f, 0.f, 0.f, 0.f};

  const int srow8 = tid >> 3;
  const int schk = (tid & 7) ^ (srow8 & 7);
  const unsigned short* aS = A + (size_t)(m0 + srow8) * K + schk * 8;
  const unsigned short* bS = Bw + (size_t)(n0 + srow8) * K + schk * 8;

  const int key0 = (quad ^ (l15 & 7)) << 4;
  const int key1 = ((4 + quad) ^ (l15 & 7)) << 4;
  const int rdA = (wm * 64 + l15) * 128;      // A region [0, 32768)
  const int rdBl = 32768 + l15 * 128;         // B region [32768, 57344)

  // B slot -> 16-col unit within the 192-col tile (in-wave rope pairing)
  constexpr int F0[6] = {0, 2, 1, 3, 4, 6};
  constexpr int F1[6] = {5, 7, 8, 10, 9, 11};

  auto stageA = [&](int bb, int tt) {  // 4 loads = 32KB (rows 0-255)
    char* d = dynlds + bb * 57344;
    const unsigned short* s = aS + (size_t)tt * 64;
    load_lds16(s, d + tid * 16);
    load_lds16(s + (size_t)64 * K, d + 8192 + tid * 16);
    load_lds16(s + (size_t)128 * K, d + 16384 + tid * 16);
    load_lds16(s + (size_t)192 * K, d + 24576 + tid * 16);
  };
  auto stageB = [&](int bb, int tt) {  // 3 loads = 24KB (rows 0-191)
    char* d = dynlds + bb * 57344 + 32768;
    const unsigned short* s = bS + (size_t)tt * 64;
    load_lds16(s, d + tid * 16);
    load_lds16(s + (size_t)64 * K, d + 8192 + tid * 16);
    load_lds16(s + (size_t)128 * K, d + 16384 + tid * 16);
  };

  // prologue: t0{A,B}->buf0, t1{A}->buf1 (11 loads); vmcnt(4) retires t0.
  stageA(0, 0); stageB(0, 0); stageA(1, 1);
  asm volatile("s_waitcnt vmcnt(4)" ::: "memory");
  __builtin_amdgcn_s_barrier();

  short8 af[4][2], bfL[3][2], bfR[3][2];
  const char* cb0 = dynlds;
  const char* cb1 = dynlds + 57344;
  const int NIT = K >> 7;  // 2 K-tiles per iteration

  for (int it = 0; it < NIT; ++it) {
    const int tO = it * 2 + 1, tE2 = it * 2 + 2, tO2 = it * 2 + 3;
    const bool STG = (it < NIT - 1);

    // ---- ph1: read af+bfL (buf0, 14); stage B(tO); lgkm; MFMA-L; BAR ----
#pragma unroll
    for (int i = 0; i < 4; ++i) {
      af[i][0] = *(const short8*)(cb0 + rdA + i * 2048 + key0);
      af[i][1] = *(const short8*)(cb0 + rdA + i * 2048 + key1);
    }
#pragma unroll
    for (int j = 0; j < 3; ++j) {
      const int fe = wn ? F1[j] : F0[j];
      bfL[j][0] = *(const short8*)(cb0 + rdBl + fe * 2048 + key0);
      bfL[j][1] = *(const short8*)(cb0 + rdBl + fe * 2048 + key1);
    }
    stageB(1, tO);
    asm volatile("s_waitcnt lgkmcnt(0)" ::: "memory");
    {
      const int JBASE = 0;
      QKV_MFMA(bfL)
    }
    __builtin_amdgcn_s_barrier();

    // ---- ph2: read bfR (buf0, 6); stage A(tE2); lgkm; MFMA-R; vmcnt; BAR ----
#pragma unroll
    for (int j = 0; j < 3; ++j) {
      const int fe = wn ? F1[3 + j] : F0[3 + j];
      bfR[j][0] = *(const short8*)(cb0 + rdBl + fe * 2048 + key0);
      bfR[j][1] = *(const short8*)(cb0 + rdBl + fe * 2048 + key1);
    }
    if (STG) stageA(0, tE2);
    asm volatile("s_waitcnt lgkmcnt(0)" ::: "memory");
    {
      const int JBASE = 3;
      QKV_MFMA(bfR)
    }
    if (STG) asm volatile("s_waitcnt vmcnt(4)" ::: "memory");
    else     asm volatile("s_waitcnt vmcnt(0)" ::: "memory");
    __builtin_amdgcn_s_barrier();  // publishes buf1

    // ---- ph3: read af+bfL (buf1, 14); stage B(tE2); lgkm; MFMA-L; BAR ----
#pragma unroll
    for (int i = 0; i < 4; ++i) {
      af[i][0] = *(const short8*)(cb1 + rdA + i * 2048 + key0);
      af[i][1] = *(const short8*)(cb1 + rdA + i * 2048 + key1);
    }
#pragma unroll
    for (int j = 0; j < 3; ++j) {
      const int fe = wn ? F1[j] : F0[j];
      bfL[j][0] = *(const short8*)(cb1 + rdBl + fe * 2048 + key0);
      bfL[j][1] = *(const short8*)(cb1 + rdBl + fe * 2048 + key1);
    }
    if (STG) stageB(0, tE2);
    asm volatile("s_waitcnt lgkmcnt(0)" ::: "memory");
    {
      const int JBASE = 0;
      QKV_MFMA(bfL)
    }
    __builtin_amdgcn_s_barrier();

    // ---- ph4: read bfR (buf1, 6); stage A(tO2); lgkm; MFMA-R; vmcnt; BAR ----
#pragma unroll
    for (int j = 0; j < 3; ++j) {
      const int fe = wn ? F1[3 + j] : F0[3 + j];
      bfR[j][0] = *(const short8*)(cb1 + rdBl + fe * 2048 + key0);
      bfR[j][1] = *(const short8*)(cb1 + rdBl + fe * 2048 + key1);
    }
    if (STG) stageA(1, tO2);
    asm volatile("s_waitcnt lgkmcnt(0)" ::: "memory");
    {
      const int JBASE = 3;
      QKV_MFMA(bfR)
    }
    if (STG) asm volatile("s_waitcnt vmcnt(4)" ::: "memory");
    else     asm volatile("s_waitcnt vmcnt(0)" ::: "memory");
    __builtin_amdgcn_s_barrier();  // publishes buf0
  }

  // ---- epilogue: per-pair region branch (head-uniform by construction) ----
#pragma unroll
  for (int i = 0; i < 4; ++i) {
    const int rowb = m0 + wm * 64 + i * 16 + quad * 4;
    const int tb = rowb & (TT - 1);
#pragma unroll
    for (int jp = 0; jp < 6; jp += 2) {
      const int fe = wn ? F1[jp] : F0[jp];
      const int col = n0 + fe * 16 + l15;
      if (col < QKN) {
        // Q or K head: RoPE (pair partner is col+32, slot jp+1)
        const float qscale = (col < KOFF) ? SCALE_Q : 1.0f;
        const int d = (fe & 3) * 16 + l15;  // 0..31
#pragma unroll
        for (int r = 0; r < 4; ++r) {
          const float2 cssn = ropeTab[(tb + r) * 32 + d];
          const float a = acc[i][jp][r], b2 = acc[i][jp + 1][r];
          const float qa = (a * cssn.x - b2 * cssn.y) * qscale;
          const float qb = (b2 * cssn.x + a * cssn.y) * qscale;
          unsigned short* p = qk + (size_t)(rowb + r) * QKN + col;
          p[0] = f2bf(qa);
          p[32] = f2bf(qb);
        }
      } else {
        // V head: transposed packed store, both slots independently
#pragma unroll
        for (int jj = jp; jj < jp + 2; ++jj) {
          const int fv = wn ? F1[jj] : F0[jj];
          const int colv = n0 + fv * 16 + l15;
          ushort4 pk;
          pk.x = f2bf(acc[i][jj][0]); pk.y = f2bf(acc[i][jj][1]);
          pk.z = f2bf(acc[i][jj][2]); pk.w = f2bf(acc[i][jj][3]);
          *(ushort4*)(vT + (size_t)(colv - 2560) * 4096 + rowb) = pk;
        }
      }
    }
  }
}

// ============================================================================
// 1b: output projection NT GEMM (f32 out) -- 256(M)x128(N) tile, 256 blocks.
// ONE barrier per phase (same restructure as gemm_qkv; queue-sim in R11).
// ============================================================================
#define NT_MFMA(J0, BF)                                                        \
  __builtin_amdgcn_s_setprio(1);                                               \
  _Pragma("unroll") for (int i_ = 0; i_ < 4; ++i_) {                           \
    _Pragma("unroll") for (int j_ = 0; j_ < 2; ++j_) {                         \
      acc[i_][(J0) + j_] = MFMA16(af[i_][0], BF[j_][0], acc[i_][(J0) + j_]);   \
      acc[i_][(J0) + j_] = MFMA16(af[i_][1], BF[j_][1], acc[i_][(J0) + j_]);   \
    }                                                                          \
  }                                                                            \
  __builtin_amdgcn_s_setprio(0);

__global__ __launch_bounds__(512, 2) void gemm_nt_f32(const unsigned short* __restrict__ A,
                                                      const unsigned short* __restrict__ Bw,
                                                      float* __restrict__ C,
                                                      int M, int N, int Kdim) {
  extern __shared__ char dynlds[];
  const int K = 2048;
  const int tid = threadIdx.x;
  const int lane = tid & 63, w = tid >> 6;
  const int quad = lane >> 4, l15 = lane & 15;
  const int wm = w >> 1, wn = w & 1;

  // XCD-bijective swizzle: 256 blocks, 32 per XCD
  const int lin = blockIdx.y * 16 + blockIdx.x;
  const int wg = (lin & 7) * 32 + (lin >> 3);
  const int m0 = (wg >> 4) * 256;
  const int n0 = (wg & 15) * 128;

  floatx4 acc[4][4];
#pragma unroll
  for (int i = 0; i < 4; ++i)
#pragma unroll
    for (int j = 0; j < 4; ++j) acc[i][j] = (floatx4){0.f, 0.f, 0.f, 0.f};

  const int srow8 = tid >> 3;
  const int schk = (tid & 7) ^ (srow8 & 7);
  const unsigned short* aS = A + (size_t)(m0 + srow8) * K + schk * 8;
  const unsigned short* bS = Bw + (size_t)(n0 + srow8) * K + schk * 8;

  const int key0 = (quad ^ (l15 & 7)) << 4;
  const int key1 = ((4 + quad) ^ (l15 & 7)) << 4;
  const int rdA = (wm * 64 + l15) * 128;          // A region: [0, 32768)
  const int rdB = 32768 + (wn * 64 + l15) * 128;  // B region: [32768, 49152)

  // stage slot: 0=A0 (rows 0-127), 1=A1 (128-255), 2=B (128 rows)
  auto stage = [&](int bb, int slot, int tt) {
    char* d = dynlds + bb * 49152 + slot * 16384;
    const unsigned short* s =
        (slot == 2 ? bS : aS + (size_t)(slot * 128) * K) + (size_t)tt * 64;
    load_lds16(s, d + tid * 16);
    load_lds16(s + (size_t)64 * K, d + 8192 + tid * 16);
  };

  // prologue: t0{A0,A1,B}->buf0, t1{A0,A1}->buf1 (10 loads); retire t0.
  stage(0, 0, 0); stage(0, 1, 0); stage(0, 2, 0);
  stage(1, 0, 1); stage(1, 1, 1);
  asm volatile("s_waitcnt vmcnt(4)" ::: "memory");
  __builtin_amdgcn_s_barrier();

  short8 af[4][2], bfL[2][2], bfR[2][2];
  const char* cb0 = dynlds;
  const char* cb1 = dynlds + 49152;
  const int NIT = K >> 7;  // 2 K-tiles per iteration

  for (int it = 0; it < NIT; ++it) {
    const int tO = it * 2 + 1, tE2 = it * 2 + 2, tO2 = it * 2 + 3;
    const bool STG = (it < NIT - 1);

    // ---- ph1: read af+bfL (buf0, 12); stage B(tO); lgkm; QL; BAR ----
#pragma unroll
    for (int i = 0; i < 4; ++i) {
      af[i][0] = *(const short8*)(cb0 + rdA + i * 2048 + key0);
      af[i][1] = *(const short8*)(cb0 + rdA + i * 2048 + key1);
    }
#pragma unroll
    for (int j = 0; j < 2; ++j) {
      bfL[j][0] = *(const short8*)(cb0 + rdB + j * 2048 + key0);
      bfL[j][1] = *(const short8*)(cb0 + rdB + j * 2048 + key1);
    }
    stage(1, 2, tO);
    asm volatile("s_waitcnt lgkmcnt(0)" ::: "memory");
    NT_MFMA(0, bfL)
    __builtin_amdgcn_s_barrier();

    // ---- ph2: read bfR (buf0, 4); stage A0,A1(tE2); lgkm; QR; vmcnt; BAR ----
#pragma unroll
    for (int j = 0; j < 2; ++j) {
      bfR[j][0] = *(const short8*)(cb0 + rdB + (2 + j) * 2048 + key0);
      bfR[j][1] = *(const short8*)(cb0 + rdB + (2 + j) * 2048 + key1);
    }
    if (STG) { stage(0, 0, tE2); stage(0, 1, tE2); }
    asm volatile("s_waitcnt lgkmcnt(0)" ::: "memory");
    NT_MFMA(2, bfR)
    if (STG) asm volatile("s_waitcnt vmcnt(4)" ::: "memory");
    else     asm volatile("s_waitcnt vmcnt(0)" ::: "memory");
    __builtin_amdgcn_s_barrier();  // publishes buf1

    // ---- ph3: read af+bfL (buf1, 12); stage B(tE2); lgkm; QL; BAR ----
#pragma unroll
    for (int i = 0; i < 4; ++i) {
      af[i][0] = *(const short8*)(cb1 + rdA + i * 2048 + key0);
      af[i][1] = *(const short8*)(cb1 + rdA + i * 2048 + key1);
    }
#pragma unroll
    for (int j = 0; j < 2; ++j) {
      bfL[j][0] = *(const short8*)(cb1 + rdB + j * 2048 + key0);
      bfL[j][1] = *(const short8*)(cb1 + rdB + j * 2048 + key1);
    }
    if (STG) stage(0, 2, tE2);
    asm volatile("s_waitcnt lgkmcnt(0)" ::: "memory");
    NT_MFMA(0, bfL)
    __builtin_amdgcn_s_barrier();

    // ---- ph4: read bfR (buf1, 4); stage A0,A1(tO2); lgkm; QR; vmcnt; BAR ----
#pragma unroll
    for (int j = 0; j < 2; ++j) {
      bfR[j][0] = *(const short8*)(cb1 + rdB + (2 + j) * 2048 + key0);
      bfR[j][1] = *(const short8*)(cb1 + rdB + (2 + j) * 2048 + key1);
    }
    if (STG) { stage(1, 0, tO2); stage(1, 1, tO2); }
    asm volatile("s_waitcnt lgkmcnt(0)" ::: "memory");
    NT_MFMA(2, bfR)
    if (STG) asm volatile("s_waitcnt vmcnt(4)" ::: "memory");
    else     asm volatile("s_waitcnt vmcnt(0)" ::: "memory");
    __builtin_amdgcn_s_barrier();  // publishes buf0
  }

  // ---- epilogue: plain f32 store ----
#pragma unroll
  for (int i = 0; i < 4; ++i) {
    const int row = m0 + wm * 64 + i * 16 + quad * 4;
#pragma unroll
    for (int j = 0; j < 4; ++j) {
      const int col = n0 + wn * 64 + j * 16 + l15;
#pragma unroll
      for (int r = 0; r < 4; ++r)
        C[(size_t)(row + r) * N + col] = acc[i][j][r];
    }
  }
}

// ---------- 2: causal flash attention v10 (REVERT to (256,3)) ----------
// R11's (256,4) spilled AGAIN (R2 failure mode: allocator splits the 128
// unified cap rigidly -> 64 arch regs, WRITE_SIZE 227MB, 112us). This
// kernel requires (256,3). DO NOT raise to 4.
// grid (32, 2, 16); P in-register via permlane transpose; raw v_exp_f32;
// epilogue rcp+mul. LDS 32768 B.
__global__ __launch_bounds__(256, 3) void attn_kernel(const unsigned short* __restrict__ qk,
                                                      const unsigned short* __restrict__ vT,
                                                      unsigned short* __restrict__ attn) {
  const int h = blockIdx.x, b = blockIdx.y;
  const int qt = 15 - (int)blockIdx.z;  // heavy-first dispatch
  const int hk = h >> 2;
  const int tid = threadIdx.x;
  const int w = tid >> 6, lane = tid & 63, quad = lane >> 4, l15 = lane & 15;

  __shared__ char lds[32768];

  const int srow = tid >> 3;                    // staging row
  const int sgrp = ((tid & 7) ^ (srow & 7));    // swizzled source col-group
  const int relbase = w * 32 + l15;             // for causal mask (q local)

  const short8 ones = {16256, 16256, 16256, 16256, 16256, 16256, 16256, 16256};  // bf16 1.0

  const size_t rowQ = (size_t)(b * TT + qt * 128);

  // ---- stage Q tile (128x64, swizzled) into K/V region ----
  {
    const unsigned short* qsrc = qk + (rowQ + srow) * QKN + h * 64 + sgrp * 8;
#pragma unroll
    for (int p = 0; p < 4; ++p)
      load_lds16(qsrc + (size_t)p * 32 * QKN, lds + p * 4096 + tid * 16);
  }
  __syncthreads();
  short8 qf[2][2];  // B-operand frags: Q[q=l15(+i*16)][d=ks*32+quad*8..]
#pragma unroll
  for (int i = 0; i < 2; ++i)
#pragma unroll
    for (int ks = 0; ks < 2; ++ks)
      qf[i][ks] = *(const short8*)(lds + (w * 32 + i * 16 + l15) * 128 +
                                   ((((ks << 2) + quad) ^ (l15 & 7)) << 4));
  __syncthreads();  // all waves done reading Q before K(0)/V(0) overwrite

  floatx4 accO[2][4], accL[2];
#pragma unroll
  for (int i = 0; i < 2; ++i) {
    accL[i] = (floatx4){0.f, 0.f, 0.f, 0.f};
#pragma unroll
    for (int j = 0; j < 4; ++j) accO[i][j] = (floatx4){0.f, 0.f, 0.f, 0.f};
  }

  // ---- prefetch pointers (advance by one 64-row tile per step) ----
  const unsigned short* kptr =
      qk + (size_t)(b * TT + srow) * QKN + KOFF + hk * 64 + sgrp * 8;
  const unsigned short* vptr =
      vT + (size_t)(hk * 64 + srow) * 4096 + b * TT + sgrp * 8;

  // ---- prologue: stage tile 0 into buf0 ----
  load_lds16(kptr, lds + tid * 16);
  load_lds16(kptr + (size_t)32 * QKN, lds + 4096 + tid * 16);
  load_lds16(vptr, lds + 16384 + tid * 16);
  load_lds16(vptr + (size_t)32 * 4096, lds + 16384 + 4096 + tid * 16);
  kptr += (size_t)64 * QKN;
  vptr += 64;
  __syncthreads();

  // one kv-tile step; BUF/PREF/MREL become compile-time after inlining
  auto step = [&](const int BUF, const bool PREF, const int MREL) {
    if (PREF) {
      char* kd = lds + ((BUF ^ 1) * 8192);
      char* vd = lds + 16384 + ((BUF ^ 1) * 8192);
      load_lds16(kptr, kd + tid * 16);
      load_lds16(kptr + (size_t)32 * QKN, kd + 4096 + tid * 16);
      load_lds16(vptr, vd + tid * 16);
      load_lds16(vptr + (size_t)32 * 4096, vd + 4096 + tid * 16);
      kptr += (size_t)64 * QKN;
      vptr += 64;
    }

    // ---- S^T = K Q^T : D[kk_local][q_local] (scale pre-folded into Q) ----
    const char* Ks = lds + BUF * 8192;
    floatx4 st[2][4];  // [i=q-tile][jm=kk-tile]
    __builtin_amdgcn_s_setprio(1);
#pragma unroll
    for (int jm = 0; jm < 4; ++jm) {
      const int krow = jm * 16 + l15;
      const short8 kf0 = *(const short8*)(Ks + krow * 128 + ((quad ^ (l15 & 7)) << 4));
      const short8 kf1 = *(const short8*)(Ks + krow * 128 + (((4 + quad) ^ (l15 & 7)) << 4));
#pragma unroll
      for (int i = 0; i < 2; ++i) {
        floatx4 z = (floatx4){0.f, 0.f, 0.f, 0.f};
        z = __builtin_amdgcn_mfma_f32_16x16x32_bf16(kf0, qf[i][0], z, 0, 0, 0);
        st[i][jm] = __builtin_amdgcn_mfma_f32_16x16x32_bf16(kf1, qf[i][1], z, 0, 0, 0);
      }
    }
    __builtin_amdgcn_s_setprio(0);

    // ---- hoist V-fragment LDS reads: latency overlaps softmax VALU ----
    const char* Vt = lds + 16384 + BUF * 8192;
    short8 vf[2][4];
#pragma unroll
    for (int ks = 0; ks < 2; ++ks)
#pragma unroll
      for (int jd = 0; jd < 4; ++jd) {
        const int d = jd * 16 + l15;
        vf[ks][jd] = *(const short8*)(Vt + d * 128 +
                                      ((((ks << 2) + quad) ^ (l15 & 7)) << 4));
      }

    // ---- softmax + in-register P transpose ----
    // source: st[i][jm][r] = P[k=jm*16+quad*4+r][q=l15]
    // target: pT[i][ks] = P[q=l15][k=32ks+8quad .. +7] (MFMA A-operand frag)
    short8 pT[2][2];
#pragma unroll
    for (int i = 0; i < 2; ++i) {
      unsigned int U[4][2];  // U[jm][h] = pack(e[2h], e[2h+1])
#pragma unroll
      for (int jm = 0; jm < 4; ++jm) {
        float e0 = __builtin_amdgcn_exp2f(st[i][jm][0]);
        float e1 = __builtin_amdgcn_exp2f(st[i][jm][1]);
        float e2 = __builtin_amdgcn_exp2f(st[i][jm][2]);
        float e3 = __builtin_amdgcn_exp2f(st[i][jm][3]);
        if (MREL >= 0) {
          const int rel = relbase + i * 16 - MREL;  // lane's local q
          const int kg = jm * 16 + quad * 4;
          if (kg > rel) e0 = 0.f;
          if (kg + 1 > rel) e1 = 0.f;
          if (kg + 2 > rel) e2 = 0.f;
          if (kg + 3 > rel) e3 = 0.f;
        }
        U[jm][0] = pack_bf16(e0, e1);
        U[jm][1] = pack_bf16(e2, e3);
      }
      // 4x4 quad-group transpose via permlane32_swap + permlane16_swap
#pragma unroll
      for (int ks = 0; ks < 2; ++ks) {
        uintx4 t;
#pragma unroll
        for (int hh = 0; hh < 2; ++hh) {
          intx2 r32 = __builtin_amdgcn_permlane32_swap(
              (int)U[2 * ks][hh], (int)U[2 * ks + 1][hh], false, false);
          intx2 r16 = __builtin_amdgcn_permlane16_swap(r32[0], r32[1], false, false);
          t[hh] = (unsigned int)r16[0];      // s = 0 + hh  (c0 = 0)
          t[2 + hh] = (unsigned int)r16[1];  // s = 2 + hh  (c0 = 1)
        }
        pT[i][ks] = __builtin_bit_cast(short8, t);
      }
    }

    // ---- O += P V ; l += P . 1 ----
    __builtin_amdgcn_s_setprio(1);
#pragma unroll
    for (int ks = 0; ks < 2; ++ks) {
      accL[0] = __builtin_amdgcn_mfma_f32_16x16x32_bf16(pT[0][ks], ones, accL[0], 0, 0, 0);
      accL[1] = __builtin_amdgcn_mfma_f32_16x16x32_bf16(pT[1][ks], ones, accL[1], 0, 0, 0);
#pragma unroll
      for (int jd = 0; jd < 4; ++jd) {
        accO[0][jd] = __builtin_amdgcn_mfma_f32_16x16x32_bf16(pT[0][ks], vf[ks][jd], accO[0][jd], 0, 0, 0);
        accO[1][jd] = __builtin_amdgcn_mfma_f32_16x16x32_bf16(pT[1][ks], vf[ks][jd], accO[1][jd], 0, 0, 0);
      }
    }
    __builtin_amdgcn_s_setprio(0);
    __syncthreads();  // drains prefetch + protects buffer overwrite
  };

  // steady: 2*qt unmasked tiles (pairs), then 2 masked diagonal tiles
  for (int t2 = 0; t2 < qt; ++t2) {
    step(0, true, -1);
    step(1, true, -1);
  }
  step(0, true, 0);
  step(1, false, 64);

  // ---- epilogue: O * (1/l) -> attn  (accL C-layout rows match accO rows) ----
#pragma unroll
  for (int i2 = 0; i2 < 2; ++i2) {
    floatx4 rl;
#pragma unroll
    for (int r = 0; r < 4; ++r) rl[r] = __builtin_amdgcn_rcpf(accL[i2][r]);
#pragma unroll
    for (int jd = 0; jd < 4; ++jd) {
      const int col = h * 64 + jd * 16 + l15;
#pragma unroll
      for (int r = 0; r < 4; ++r) {
        const size_t row = rowQ + w * 32 + i2 * 16 + quad * 4 + r;
        attn[row * TC + col] = f2bf(accO[i2][jd][r] * rl[r]);
      }
    }
  }
}

// ---------- launch ----------
extern "C" void kernel_launch(void* const* d_in, const int* in_sizes, int n_in,
                              void* d_out, int out_size, void* d_ws, size_t ws_size,
                              hipStream_t stream) {
  const float* x = (const float*)d_in[0];
  const float* Wq = (const float*)d_in[1];
  const float* Wk = (const float*)d_in[2];
  const float* Wv = (const float*)d_in[3];
  const float* Wo = (const float*)d_in[4];
  float* out = (float*)d_out;

  char* ws = (char*)d_ws;
  unsigned short* xb   = (unsigned short*)(ws);               // 4096x2048 bf16
  unsigned short* wqkv = (unsigned short*)(ws + 16777216);    // 3072x2048 bf16
  unsigned short* wob  = (unsigned short*)(ws + 29360128);    // 2048x2048 bf16
  unsigned short* qk   = (unsigned short*)(ws + 37748736);    // 4096x2560 bf16 (Q|K, roped)
  unsigned short* vT   = (unsigned short*)(ws + 58720256);    // 512x4096 bf16 (V transposed)
  unsigned short* attn = (unsigned short*)(ws + 62914560);    // 4096x2048 bf16
  // rope table (512 KB) overlays the attn buffer: written by cast_all, read by
  // gemm_qkv, then overwritten by attn_kernel (all stream-ordered).
  float2* ropeTab = (float2*)(ws + 62914560);
  // total ws use: 79,691,776 bytes

  cast_all<<<18432, 256, 0, stream>>>(x, Wq, Wk, Wv, Wo, xb, wqkv, wob, ropeTab);
  gemm_qkv<<<dim3(16, 16), 512, 114688, stream>>>(xb, wqkv, qk, vT, ropeTab);
  attn_kernel<<<dim3(32, 2, 16), 256, 0, stream>>>(qk, vT, attn);
  gemm_nt_f32<<<dim3(16, 16), 512, 98304, stream>>>(attn, wob, out, 4096, TC, 2048);
}